// Round 2
// baseline (2401.766 us; speedup 1.0000x reference)
//
#include <hip/hip_runtime.h>
#include <hip/hip_bf16.h>

// LTC fused scan, round 2.
// B=512 rows, one 512-thread workgroup (8 waves) per row.
// lane = unit j (U=64). Wave w owns sensory i in [16w,16w+16),
// recurrent i in [8w,8w+8).
// Sigmoid terms: s = 1/(1+exp2(a*v+c)), a=-log2e*sigma, c=log2e*sigma*mu.
// 4-way batched reciprocal: one v_rcp per 4 terms (exact math).
// (num,den) accumulated as float2 -> v_pk_fma_f32 with (w*erev, w) packed.

#define NB 512
#define NT 512
#define NI 128
#define NU 64
#define NO 15
#define L2E 1.44269504088896340736f

typedef float v2f __attribute__((ext_vector_type(2)));

__device__ __forceinline__ float bcastf(float v, int lane) {
  return __int_as_float(__builtin_amdgcn_readlane(__float_as_int(v), lane));
}

__device__ __forceinline__ float wsum64(float x) {
#pragma unroll
  for (int m = 32; m >= 1; m >>= 1) x += __shfl_xor(x, m, 64);
  return x;
}

__device__ __forceinline__ float softplus_f(float x) {
  return log1pf(expf(x));
}

// 4 sigmoids s_i = 1/(1+e_i), e_i = exp2(z_i), with ONE v_rcp via product tree.
__device__ __forceinline__ void sig4(float z0, float z1, float z2, float z3,
                                     float& s0, float& s1, float& s2, float& s3) {
  const float e0 = __builtin_amdgcn_exp2f(z0);
  const float e1 = __builtin_amdgcn_exp2f(z1);
  const float e2 = __builtin_amdgcn_exp2f(z2);
  const float e3 = __builtin_amdgcn_exp2f(z3);
  const float A = 1.0f + e0, B = 1.0f + e1, C = 1.0f + e2, D = 1.0f + e3;
  const float pAB = A * B, pCD = C * D;
  const float r = __builtin_amdgcn_rcpf(pAB * pCD);
  const float rAB = r * pCD, rCD = r * pAB;   // 1/(AB), 1/(CD)
  s0 = rAB * B; s1 = rAB * A; s2 = rCD * D; s3 = rCD * C;
}

__global__ __launch_bounds__(512, 4) void ltc_fused(
    const float* __restrict__ x,
    const float* __restrict__ input_w, const float* __restrict__ input_b,
    const float* __restrict__ sensory_w, const float* __restrict__ sensory_mu,
    const float* __restrict__ sensory_sigma, const float* __restrict__ sensory_erev,
    const float* __restrict__ w_, const float* __restrict__ mu_,
    const float* __restrict__ sigma_, const float* __restrict__ erev_,
    const float* __restrict__ gleak, const float* __restrict__ vleak,
    const float* __restrict__ cm,
    const float* __restrict__ output_w, const float* __restrict__ output_b,
    const float* __restrict__ ln_w, const float* __restrict__ ln_b,
    const float* __restrict__ fc_w, const float* __restrict__ fc_b,
    float* __restrict__ out)
{
  const int b    = blockIdx.x;
  const int tid  = threadIdx.x;
  const int wv   = tid >> 6;     // wave 0..7
  const int lane = tid & 63;     // unit j

  __shared__ v2f xbuf[4][8][NU];   // [unfold][wave][lane] partial (num,den)

  // ---- sensory params: i = 16*wv + k, j = lane ----
  float sa[16], sc[16];
  v2f   sw2[16];                   // (softplus(w)*erev, softplus(w))
#pragma unroll
  for (int k = 0; k < 16; ++k) {
    const int idx = (16 * wv + k) * NU + lane;
    const float ss = sensory_sigma[idx];
    const float sm = sensory_mu[idx];
    const float sw = softplus_f(sensory_w[idx]);
    const float se = sensory_erev[idx];
    sa[k] = -L2E * ss;
    sc[k] =  L2E * ss * sm;
    sw2[k] = (v2f){sw * se, sw};
  }
  // ---- recurrent params: i = 8*wv + k, j = lane ----
  float ra[8], rc[8];
  v2f   rw2[8];
#pragma unroll
  for (int k = 0; k < 8; ++k) {
    const int idx = (8 * wv + k) * NU + lane;
    const float sg = sigma_[idx];
    const float m  = mu_[idx];
    const float ww = softplus_f(w_[idx]);
    const float ev = erev_[idx];
    ra[k] = -L2E * sg;
    rc[k] =  L2E * sg * m;
    rw2[k] = (v2f){ww * ev, ww};
  }

  // ---- per-neuron constants (lane = j) ----
  const float glp   = softplus_f(gleak[lane]);
  const float cmt   = softplus_f(cm[lane]) * 4.0f;
  const float glvl  = glp * vleak[lane];
  const float dbase = cmt + glp + 1e-8f;

  // lane's sensory input index (lanes 16..63 duplicate 0..15)
  const int ii = 16 * wv + (lane & 15);
  const float iw = input_w[ii];
  const float ib = input_b[ii];

  float v = 0.0f;
  const float* xp = x + (size_t)b * NT * NI + ii;
  float xv = xp[0];

#pragma unroll 1
  for (int t = 0; t < NT; ++t) {
    const int tn = (t + 1 < NT) ? (t + 1) : t;
    const float xv_next = xp[(size_t)tn * NI];
    const float inp = fmaf(xv, iw, ib);

    // ---- sensory: 16 terms = 4 batches of 4 ----
    v2f sens = (v2f){0.0f, 0.0f};
#pragma unroll
    for (int k = 0; k < 16; k += 4) {
      float z0 = fmaf(sa[k+0], bcastf(inp, k+0), sc[k+0]);
      float z1 = fmaf(sa[k+1], bcastf(inp, k+1), sc[k+1]);
      float z2 = fmaf(sa[k+2], bcastf(inp, k+2), sc[k+2]);
      float z3 = fmaf(sa[k+3], bcastf(inp, k+3), sc[k+3]);
      // clamp: |x| can reach ~5.5 -> |z| up to ~60; keep 4-term product finite
      z0 = fminf(fmaxf(z0, -30.0f), 30.0f);
      z1 = fminf(fmaxf(z1, -30.0f), 30.0f);
      z2 = fminf(fmaxf(z2, -30.0f), 30.0f);
      z3 = fminf(fmaxf(z3, -30.0f), 30.0f);
      float s0, s1, s2, s3;
      sig4(z0, z1, z2, z3, s0, s1, s2, s3);
      sens += sw2[k+0] * (v2f){s0, s0};
      sens += sw2[k+1] * (v2f){s1, s1};
      sens += sw2[k+2] * (v2f){s2, s2};
      sens += sw2[k+3] * (v2f){s3, s3};
    }

    // ---- 4 ODE unfolds ----
#pragma unroll
    for (int u = 0; u < 4; ++u) {
      const int i0 = 8 * wv;
      v2f acc = sens;
#pragma unroll
      for (int k = 0; k < 8; k += 4) {
        // recurrent z is bounded (|v|<=1): |z| <= ~21, product <= 2^84, no clamp
        const float z0 = fmaf(ra[k+0], bcastf(v, i0+k+0), rc[k+0]);
        const float z1 = fmaf(ra[k+1], bcastf(v, i0+k+1), rc[k+1]);
        const float z2 = fmaf(ra[k+2], bcastf(v, i0+k+2), rc[k+2]);
        const float z3 = fmaf(ra[k+3], bcastf(v, i0+k+3), rc[k+3]);
        float s0, s1, s2, s3;
        sig4(z0, z1, z2, z3, s0, s1, s2, s3);
        acc += rw2[k+0] * (v2f){s0, s0};
        acc += rw2[k+1] * (v2f){s1, s1};
        acc += rw2[k+2] * (v2f){s2, s2};
        acc += rw2[k+3] * (v2f){s3, s3};
      }
      xbuf[u][wv][lane] = acc;
      __syncthreads();
      v2f tot = xbuf[u][0][lane];
#pragma unroll
      for (int p = 1; p < 8; ++p) tot += xbuf[u][p][lane];
      const float num = fmaf(cmt, v, glvl) + tot.x;
      const float den = dbase + tot.y;
      v = num * __builtin_amdgcn_rcpf(den);
      // next write to xbuf[u] is 4 barriers away -> no WAR hazard
    }
    xv = xv_next;
  }

  // ---- head: affine out-map, LayerNorm(eps=1e-5), fc (O=15) ----
  if (wv == 0) {
    const float h    = fmaf(v, output_w[lane], output_b[lane]);
    const float mean = wsum64(h) * (1.0f / 64.0f);
    const float d    = h - mean;
    const float var  = wsum64(d * d) * (1.0f / 64.0f);
    const float hn   = d * rsqrtf(var + 1e-5f) * ln_w[lane] + ln_b[lane];
#pragma unroll
    for (int o = 0; o < NO; ++o) {
      const float p = wsum64(hn * fc_w[o * NU + lane]);
      if (lane == 0) out[b * NO + o] = p + fc_b[o];
    }
  }
}

extern "C" void kernel_launch(void* const* d_in, const int* in_sizes, int n_in,
                              void* d_out, int out_size, void* d_ws, size_t ws_size,
                              hipStream_t stream) {
  const float* x             = (const float*)d_in[0];
  const float* input_w       = (const float*)d_in[1];
  const float* input_b       = (const float*)d_in[2];
  const float* sensory_w     = (const float*)d_in[3];
  const float* sensory_mu    = (const float*)d_in[4];
  const float* sensory_sigma = (const float*)d_in[5];
  const float* sensory_erev  = (const float*)d_in[6];
  const float* w_            = (const float*)d_in[7];
  const float* mu_           = (const float*)d_in[8];
  const float* sigma_        = (const float*)d_in[9];
  const float* erev_         = (const float*)d_in[10];
  const float* gleak         = (const float*)d_in[11];
  const float* vleak         = (const float*)d_in[12];
  const float* cm            = (const float*)d_in[13];
  const float* output_w      = (const float*)d_in[14];
  const float* output_b      = (const float*)d_in[15];
  const float* ln_w          = (const float*)d_in[16];
  const float* ln_b          = (const float*)d_in[17];
  const float* fc_w          = (const float*)d_in[18];
  const float* fc_b          = (const float*)d_in[19];
  float* out = (float*)d_out;

  ltc_fused<<<dim3(NB), dim3(512), 0, stream>>>(
      x, input_w, input_b, sensory_w, sensory_mu, sensory_sigma, sensory_erev,
      w_, mu_, sigma_, erev_, gleak, vleak, cm, output_w, output_b,
      ln_w, ln_b, fc_w, fc_b, out);
}